// Round 1
// baseline (740.209 us; speedup 1.0000x reference)
//
#include <hip/hip_runtime.h>

// FlowExp: v = flow/2^8; repeat 8x: v <- trilinear_pull(v, identity + v)
// (circular wrap indexing, zero where sample coord outside [0, n-1]).
// Output channel-first (B,3,D,H,W).

#define BB 2
#define DD 160
#define HH 192
#define WW 160

constexpr int PLANE = DD * HH * WW;      // 4,915,200
constexpr int NVOX  = BB * PLANE;        // 9,830,400

__device__ __forceinline__ int wrapi(int i, int n) {
    int m = i % n;
    return m < 0 ? m + n : m;
}

// IN_PLANAR: input is (B,3,D,H,W) with per-element scale (step 1 reads flow).
// OUT_PLANAR: output written (B,3,D,H,W) (final step), else interleaved (B,D,H,W,3).
template<bool IN_PLANAR, bool OUT_PLANAR>
__global__ __launch_bounds__(256) void flow_step(const float* __restrict__ vin,
                                                 float* __restrict__ vout,
                                                 float scale) {
    int t = blockIdx.x * blockDim.x + threadIdx.x;
    if (t >= NVOX) return;
    int x = t % WW;
    int r = t / WW;
    int y = r % HH;
    r /= HH;
    int z = r % DD;
    int b = r / DD;

    // own-voxel displacement
    float vz, vy, vx;
    if (IN_PLANAR) {
        const float* base = vin + b * 3 * PLANE + (z * HH + y) * WW + x;
        vz = base[0] * scale;
        vy = base[PLANE] * scale;
        vx = base[2 * PLANE] * scale;
    } else {
        const float* base = vin + t * 3;
        vz = base[0];
        vy = base[1];
        vx = base[2];
    }

    float cz = (float)z + vz;
    float cy = (float)y + vy;
    float cx = (float)x + vx;

    float oz = 0.f, oy = 0.f, ox = 0.f;

    bool inb = (cz >= 0.f) && (cz <= (float)(DD - 1)) &&
               (cy >= 0.f) && (cy <= (float)(HH - 1)) &&
               (cx >= 0.f) && (cx <= (float)(WW - 1));

    if (inb) {
        float fz = floorf(cz), fy = floorf(cy), fx = floorf(cx);
        float gz = cz - fz, gy = cy - fy, gx = cx - fx;
        int iz = (int)fz, iy = (int)fy, ix = (int)fx;

        int zi[2] = { wrapi(iz, DD), wrapi(iz + 1, DD) };
        int yi[2] = { wrapi(iy, HH), wrapi(iy + 1, HH) };
        int xi[2] = { wrapi(ix, WW), wrapi(ix + 1, WW) };
        float wzv[2] = { 1.f - gz, gz };
        float wyv[2] = { 1.f - gy, gy };
        float wxv[2] = { 1.f - gx, gx };

        // corner order matches reference: dz outer, dy mid, dx inner
        #pragma unroll
        for (int dz = 0; dz < 2; ++dz) {
            #pragma unroll
            for (int dy = 0; dy < 2; ++dy) {
                #pragma unroll
                for (int dx = 0; dx < 2; ++dx) {
                    float w = (wzv[dz] * wyv[dy]) * wxv[dx];
                    float sz, sy, sx;
                    if (IN_PLANAR) {
                        int p = b * 3 * PLANE + (zi[dz] * HH + yi[dy]) * WW + xi[dx];
                        sz = vin[p] * scale;
                        sy = vin[p + PLANE] * scale;
                        sx = vin[p + 2 * PLANE] * scale;
                    } else {
                        int p = (((b * DD + zi[dz]) * HH + yi[dy]) * WW + xi[dx]) * 3;
                        sz = vin[p];
                        sy = vin[p + 1];
                        sx = vin[p + 2];
                    }
                    oz += sz * w;
                    oy += sy * w;
                    ox += sx * w;
                }
            }
        }
    }

    if (OUT_PLANAR) {
        float* base = vout + b * 3 * PLANE + (z * HH + y) * WW + x;
        base[0] = oz;
        base[PLANE] = oy;
        base[2 * PLANE] = ox;
    } else {
        float* base = vout + t * 3;
        base[0] = oz;
        base[1] = oy;
        base[2] = ox;
    }
}

extern "C" void kernel_launch(void* const* d_in, const int* in_sizes, int n_in,
                              void* d_out, int out_size, void* d_ws, size_t ws_size,
                              hipStream_t stream) {
    const float* flow = (const float*)d_in[0];
    float* out = (float*)d_out;   // doubles as interleaved scratch for even steps
    float* wsA = (float*)d_ws;    // interleaved scratch (needs NVOX*3*4 = 118 MB)

    dim3 blk(256);
    dim3 grd((NVOX + 255) / 256);
    const float s = 1.f / 256.f;  // 1 / 2^NSTEPS

    // step 1: flow (planar, scaled) -> wsA (interleaved)
    flow_step<true,  false><<<grd, blk, 0, stream>>>(flow, wsA, s);
    // steps 2..7: ping-pong wsA <-> out (interleaved scratch)
    flow_step<false, false><<<grd, blk, 0, stream>>>(wsA, out, 1.f);
    flow_step<false, false><<<grd, blk, 0, stream>>>(out, wsA, 1.f);
    flow_step<false, false><<<grd, blk, 0, stream>>>(wsA, out, 1.f);
    flow_step<false, false><<<grd, blk, 0, stream>>>(out, wsA, 1.f);
    flow_step<false, false><<<grd, blk, 0, stream>>>(wsA, out, 1.f);
    flow_step<false, false><<<grd, blk, 0, stream>>>(out, wsA, 1.f);
    // step 8: wsA -> out in planar (B,3,D,H,W) layout
    flow_step<false, true ><<<grd, blk, 0, stream>>>(wsA, out, 1.f);
}